// Round 1
// baseline (1139.020 us; speedup 1.0000x reference)
//
#include <hip/hip_runtime.h>
#include <math.h>

#define N_NODES 100000
#define N_EDGES 1600000
#define IN_DIM  512
#define OUT_DIM 128

// ---------------- ws layout (4-byte units) ----------------
// [0      , 100000) deg1 (int)
// [100000 , 200000) deg2 (int)
// [200000 , 200512) s1   (float, sum_v deg1[v]*feat[v])
// [200512 , 201024) s2   (float)
// [201024 , 202048) wv   (float: w12[512] | w21[512])
// [202048 , 202050) alpha(float: a1, a2)
// [202112 , 602112) p    (float: p_f1[N] | p_f2[N] | p_s1[N] | p_s2[N])

__global__ void k_zero(float* __restrict__ p, int n) {
    int i = blockIdx.x * blockDim.x + threadIdx.x;
    if (i < n) p[i] = 0.0f;
}

__global__ void k_deg(const int* __restrict__ src1, const int* __restrict__ src2,
                      int* __restrict__ deg1, int* __restrict__ deg2) {
    int i = blockIdx.x * blockDim.x + threadIdx.x;
    if (i < N_EDGES) {
        atomicAdd(&deg1[src1[i]], 1);
        atomicAdd(&deg2[src2[i]], 1);
    }
}

// 128 threads/block; thread t owns dims [4t, 4t+4). One 2KB row per block-iter.
__global__ void k_wsum(const float* __restrict__ feat,
                       const int* __restrict__ deg1, const int* __restrict__ deg2,
                       float* __restrict__ s1, float* __restrict__ s2) {
    const int k = 4 * threadIdx.x;
    float4 a1 = {0.f, 0.f, 0.f, 0.f};
    float4 a2 = {0.f, 0.f, 0.f, 0.f};
    for (int v = blockIdx.x; v < N_NODES; v += gridDim.x) {
        float d1 = (float)deg1[v];
        float d2 = (float)deg2[v];
        float4 f = *reinterpret_cast<const float4*>(feat + (size_t)v * IN_DIM + k);
        a1.x += d1 * f.x; a1.y += d1 * f.y; a1.z += d1 * f.z; a1.w += d1 * f.w;
        a2.x += d2 * f.x; a2.y += d2 * f.y; a2.z += d2 * f.z; a2.w += d2 * f.w;
    }
    atomicAdd(&s1[k],     a1.x); atomicAdd(&s1[k + 1], a1.y);
    atomicAdd(&s1[k + 2], a1.z); atomicAdd(&s1[k + 3], a1.w);
    atomicAdd(&s2[k],     a2.x); atomicAdd(&s2[k + 1], a2.y);
    atomicAdd(&s2[k + 2], a2.z); atomicAdd(&s2[k + 3], a2.w);
}

// Single block, 256 threads: c = sigmoid(s@W/N + b); u = Wb@c; w = W@u; alpha = b.u + bb
__global__ void k_prep(const float* __restrict__ s1, const float* __restrict__ s2,
                       const float* __restrict__ W1, const float* __restrict__ b1,
                       const float* __restrict__ W2, const float* __restrict__ b2,
                       const float* __restrict__ Wb, const float* __restrict__ bb,
                       float* __restrict__ wv, float* __restrict__ alpha) {
    __shared__ float ls1[IN_DIM], ls2[IN_DIM];
    __shared__ float c1[OUT_DIM], c2[OUT_DIM], u1[OUT_DIM], u2[OUT_DIM];
    const int t = threadIdx.x;  // 0..255
    for (int k = t; k < IN_DIM; k += 256) { ls1[k] = s1[k]; ls2[k] = s2[k]; }
    __syncthreads();
    if (t < OUT_DIM) {
        float acc1 = 0.f, acc2 = 0.f;
        for (int k = 0; k < IN_DIM; k++) {
            acc1 += ls1[k] * W1[k * OUT_DIM + t];
            acc2 += ls2[k] * W2[k * OUT_DIM + t];
        }
        float m1 = acc1 * (1.0f / N_NODES) + b1[t];
        float m2 = acc2 * (1.0f / N_NODES) + b2[t];
        c1[t] = 1.0f / (1.0f + expf(-m1));
        c2[t] = 1.0f / (1.0f + expf(-m2));
    }
    __syncthreads();
    if (t < OUT_DIM) {
        // u[d] = sum_e Wb[d,e] * c[e]
        float a1 = 0.f, a2 = 0.f;
        for (int e = 0; e < OUT_DIM; e++) {
            float w = Wb[t * OUT_DIM + e];
            a1 += w * c1[e];
            a2 += w * c2[e];
        }
        u1[t] = a1; u2[t] = a2;
    }
    __syncthreads();
    // w12[k] = sum_d W1[k,d] u2[d]  (for sc2/sc4);  w21[k] = sum_d W2[k,d] u1[d] (for sc1/sc3)
    for (int k = t; k < IN_DIM; k += 256) {
        float a12 = 0.f, a21 = 0.f;
        for (int d = 0; d < OUT_DIM; d++) {
            a12 += W1[k * OUT_DIM + d] * u2[d];
            a21 += W2[k * OUT_DIM + d] * u1[d];
        }
        wv[k] = a12;            // w12
        wv[IN_DIM + k] = a21;   // w21
    }
    if (t == 0) {
        float a1 = 0.f, a2 = 0.f;
        for (int d = 0; d < OUT_DIM; d++) {
            a1 += b2[d] * u1[d];   // constant of sc1/sc3
            a2 += b1[d] * u2[d];   // constant of sc2/sc4
        }
        alpha[0] = a1 + bb[0];
        alpha[1] = a2 + bb[0];
    }
}

// One wave per row; lane l owns dims [4l,4l+4) and [256+4l, 256+4l+4).
__global__ void k_proj(const float* __restrict__ feat, const float* __restrict__ shuf,
                       const float* __restrict__ wv, float* __restrict__ p) {
    const int lane  = threadIdx.x & 63;
    const int gwave = (blockIdx.x * blockDim.x + threadIdx.x) >> 6;
    const int nw    = (gridDim.x * blockDim.x) >> 6;
    const int kA = 4 * lane;
    const int kB = 256 + 4 * lane;
    const float4 w12a = *(const float4*)(wv + kA);
    const float4 w12b = *(const float4*)(wv + kB);
    const float4 w21a = *(const float4*)(wv + IN_DIM + kA);
    const float4 w21b = *(const float4*)(wv + IN_DIM + kB);
    for (int r = gwave; r < 2 * N_NODES; r += nw) {
        const float* row = (r < N_NODES)
            ? (feat + (size_t)r * IN_DIM)
            : (shuf + (size_t)(r - N_NODES) * IN_DIM);
        float4 fa = *(const float4*)(row + kA);
        float4 fb = *(const float4*)(row + kB);
        float d12 = fa.x * w12a.x + fa.y * w12a.y + fa.z * w12a.z + fa.w * w12a.w
                  + fb.x * w12b.x + fb.y * w12b.y + fb.z * w12b.z + fb.w * w12b.w;
        float d21 = fa.x * w21a.x + fa.y * w21a.y + fa.z * w21a.z + fa.w * w21a.w
                  + fb.x * w21b.x + fb.y * w21b.y + fb.z * w21b.z + fb.w * w21b.w;
#pragma unroll
        for (int off = 32; off > 0; off >>= 1) {
            d12 += __shfl_down(d12, off);
            d21 += __shfl_down(d21, off);
        }
        if (lane == 0) {
            if (r < N_NODES) {
                p[r] = d12;                      // p_f1[v] = feat[v].w12
                p[N_NODES + r] = d21;            // p_f2[v] = feat[v].w21
            } else {
                p[N_NODES + r] = d12;            // p_s1[v] = shuf[v].w12  (at 2N+v)
                p[2 * N_NODES + r] = d21;        // p_s2[v] = shuf[v].w21  (at 3N+v)
            }
        }
    }
}

__global__ void k_init(float* __restrict__ out, const float* __restrict__ alpha) {
    int i = blockIdx.x * blockDim.x + threadIdx.x;
    if (i < 4 * N_NODES) {
        int sec = i / N_NODES;          // 0:sc1 1:sc2 2:sc3 3:sc4
        out[i] = alpha[sec & 1];        // sc1,sc3 -> alpha[0]; sc2,sc4 -> alpha[1]
    }
}

__global__ void k_scatter(const int* __restrict__ src1, const int* __restrict__ dst1,
                          const int* __restrict__ src2, const int* __restrict__ dst2,
                          const float* __restrict__ p, float* __restrict__ out) {
    int i = blockIdx.x * blockDim.x + threadIdx.x;
    if (i < N_EDGES) {
        int s1 = src1[i], d1 = dst1[i];
        int s2 = src2[i], d2 = dst2[i];
        atomicAdd(&out[d2],                 p[N_NODES + s2]);      // sc1: h2.u1
        atomicAdd(&out[N_NODES + d1],       p[s1]);                // sc2: h1.u2
        atomicAdd(&out[2 * N_NODES + d2],   p[3 * N_NODES + s2]);  // sc3: h4.u1
        atomicAdd(&out[3 * N_NODES + d1],   p[2 * N_NODES + s1]);  // sc4: h3.u2
    }
}

extern "C" void kernel_launch(void* const* d_in, const int* in_sizes, int n_in,
                              void* d_out, int out_size, void* d_ws, size_t ws_size,
                              hipStream_t stream) {
    const float* feat = (const float*)d_in[0];
    const float* shuf = (const float*)d_in[1];
    const int* src1 = (const int*)d_in[2];
    const int* dst1 = (const int*)d_in[3];
    const int* src2 = (const int*)d_in[4];
    const int* dst2 = (const int*)d_in[5];
    const float* W1 = (const float*)d_in[6];
    const float* b1 = (const float*)d_in[7];
    const float* W2 = (const float*)d_in[8];
    const float* b2 = (const float*)d_in[9];
    const float* Wb = (const float*)d_in[10];
    const float* bb = (const float*)d_in[11];
    float* out = (float*)d_out;

    float* wsf   = (float*)d_ws;
    int*   deg1  = (int*)d_ws;
    int*   deg2  = deg1 + N_NODES;
    float* s1    = wsf + 200000;
    float* s2    = wsf + 200512;
    float* wv    = wsf + 201024;
    float* alpha = wsf + 202048;
    float* p     = wsf + 202112;

    // 1. zero accumulators (deg1, deg2, s1, s2)
    k_zero<<<(201024 + 255) / 256, 256, 0, stream>>>(wsf, 201024);
    // 2. out-degree histograms
    k_deg<<<(N_EDGES + 255) / 256, 256, 0, stream>>>(src1, src2, deg1, deg2);
    // 3. degree-weighted feature sums
    k_wsum<<<2048, 128, 0, stream>>>(feat, deg1, deg2, s1, s2);
    // 4. closed-form small math: c, u, w vectors, alpha constants
    k_prep<<<1, 256, 0, stream>>>(s1, s2, W1, b1, W2, b2, Wb, bb, wv, alpha);
    // 5. per-node scalar projections (one pass over feat + shuf)
    k_proj<<<8192, 256, 0, stream>>>(feat, shuf, wv, p);
    // 6. init output with constants
    k_init<<<(4 * N_NODES + 255) / 256, 256, 0, stream>>>(out, alpha);
    // 7. scalar segment-sum scatter
    k_scatter<<<(N_EDGES + 255) / 256, 256, 0, stream>>>(src1, dst1, src2, dst2, p, out);
}

// Round 2
// 1115.711 us; speedup vs baseline: 1.0209x; 1.0209x over previous
//
#include <hip/hip_runtime.h>
#include <math.h>

#define N_NODES 100000
#define N_EDGES 1600000
#define IN_DIM  512
#define OUT_DIM 128

// ---------------- ws layout (float offsets) ----------------
#define OFF_S1    0        // 512 floats: sum_v deg1[v]*feat[v]
#define OFF_S2    512      // 512
#define OFF_M     1024     // m[2][128]  (s @ W, pre-sigmoid, unscaled)
#define OFF_U     1280     // u[2][128]  (u1 = Wb@c1, u2 = Wb@c2)
#define OFF_WV    1536     // w12[512] | w21[512]
#define OFF_ALPHA 2560     // alpha[2]
#define OFF_PA    4096     // float2[N]: {p_f2[v], p_s2[v]}  (consumed via src2)
#define OFF_PB    204096   // float2[N]: {p_f1[v], p_s1[v]}  (consumed via src1)
#define OFF_DEG   404096   // Rdeg * 200000 ints (per r: deg1[100000] | deg2[100000])
// ACC at OFF_DEG + Rdeg*200000: Racc * 400000 floats (per r: accA f2[N] | accB f2[N])

__global__ void k_zero(float4* __restrict__ hdr, float4* __restrict__ tail,
                       int n_hdr4, long n_tail4) {
    long i = (long)blockIdx.x * blockDim.x + threadIdx.x;
    long stride = (long)gridDim.x * blockDim.x;
    float4 z = {0.f, 0.f, 0.f, 0.f};
    long tot = n_hdr4 + n_tail4;
    for (long j = i; j < tot; j += stride) {
        if (j < n_hdr4) hdr[j] = z;
        else tail[j - n_hdr4] = z;
    }
}

// 2 edges per thread; per-wave replica spreads same-address collisions.
__global__ void k_deg(const int* __restrict__ src1, const int* __restrict__ src2,
                      int* __restrict__ deg, int rmask) {
    int i = blockIdx.x * blockDim.x + threadIdx.x;
    int r = (i >> 6) & rmask;
    int* d = deg + (size_t)r * 200000;
    int e = 2 * i;
    if (e < N_EDGES) {
        int2 s1 = *(const int2*)(src1 + e);
        int2 s2 = *(const int2*)(src2 + e);
        atomicAdd(&d[s1.x], 1);
        atomicAdd(&d[s1.y], 1);
        atomicAdd(&d[100000 + s2.x], 1);
        atomicAdd(&d[100000 + s2.y], 1);
    }
}

// 128 threads/block; thread t owns dims [4t,4t+4). Sums deg over replicas inline.
__global__ void k_wsum(const float* __restrict__ feat, const int* __restrict__ deg,
                       int R, float* __restrict__ s1, float* __restrict__ s2) {
    const int k = 4 * threadIdx.x;
    float4 a1 = {0.f, 0.f, 0.f, 0.f};
    float4 a2 = {0.f, 0.f, 0.f, 0.f};
    for (int v = blockIdx.x; v < N_NODES; v += gridDim.x) {
        int id1 = 0, id2 = 0;
        for (int r = 0; r < R; ++r) {
            id1 += deg[(size_t)r * 200000 + v];
            id2 += deg[(size_t)r * 200000 + 100000 + v];
        }
        float d1 = (float)id1, d2 = (float)id2;
        float4 f = *reinterpret_cast<const float4*>(feat + (size_t)v * IN_DIM + k);
        a1.x += d1 * f.x; a1.y += d1 * f.y; a1.z += d1 * f.z; a1.w += d1 * f.w;
        a2.x += d2 * f.x; a2.y += d2 * f.y; a2.z += d2 * f.z; a2.w += d2 * f.w;
    }
    atomicAdd(&s1[k],     a1.x); atomicAdd(&s1[k + 1], a1.y);
    atomicAdd(&s1[k + 2], a1.z); atomicAdd(&s1[k + 3], a1.w);
    atomicAdd(&s2[k],     a2.x); atomicAdd(&s2[k + 1], a2.y);
    atomicAdd(&s2[k + 2], a2.z); atomicAdd(&s2[k + 3], a2.w);
}

// grid (16,2) x 128 thr: m[mat][t] = sum_k s[mat][k] * W[k*128+t]  (32 blocks parallel)
__global__ void k_gemv_m(const float* __restrict__ ws, const float* __restrict__ W1,
                         const float* __restrict__ W2, float* __restrict__ m) {
    const int mat = blockIdx.y;
    const float* W = mat ? W2 : W1;
    const float* s = ws + (mat ? OFF_S2 : OFF_S1);
    const int t = threadIdx.x;
    const int k0 = blockIdx.x * 32;
    float acc = 0.f;
#pragma unroll 8
    for (int j = 0; j < 32; ++j)
        acc += s[k0 + j] * W[(k0 + j) * OUT_DIM + t];
    atomicAdd(&m[mat * OUT_DIM + t], acc);
}

// grid 2 x 128: c = sigmoid(m/N + b); u = Wb@c; alpha[mat] = b_other . u + bb
__global__ void k_u(float* __restrict__ ws, const float* __restrict__ b1,
                    const float* __restrict__ b2, const float* __restrict__ Wb,
                    const float* __restrict__ bb) {
    __shared__ float c[OUT_DIM];
    __shared__ float red[128];
    const int mat = blockIdx.x;
    const int t = threadIdx.x;
    const float* b = mat ? b2 : b1;
    float mv = ws[OFF_M + mat * OUT_DIM + t] * (1.0f / N_NODES) + b[t];
    c[t] = 1.0f / (1.0f + expf(-mv));
    __syncthreads();
    float acc = 0.f;
    const float4* wr = (const float4*)(Wb + t * OUT_DIM);
#pragma unroll 8
    for (int j = 0; j < OUT_DIM / 4; ++j) {
        float4 w = wr[j];
        acc += w.x * c[4 * j] + w.y * c[4 * j + 1] + w.z * c[4 * j + 2] + w.w * c[4 * j + 3];
    }
    ws[OFF_U + mat * OUT_DIM + t] = acc;   // mat0: u1, mat1: u2
    const float* bo = mat ? b1 : b2;       // alpha0 = b2.u1+bb ; alpha1 = b1.u2+bb
    red[t] = bo[t] * acc;
    __syncthreads();
    for (int s = 64; s > 0; s >>= 1) {
        if (t < s) red[t] += red[t + s];
        __syncthreads();
    }
    if (t == 0) ws[OFF_ALPHA + mat] = red[0] + bb[0];
}

// 1024 waves, one per (mat,k): w12[k]=W1_row_k.u2 ; w21[k]=W2_row_k.u1
__global__ void k_w(const float* __restrict__ ws, const float* __restrict__ W1,
                    const float* __restrict__ W2, float* __restrict__ wv) {
    const int wid = (blockIdx.x * blockDim.x + threadIdx.x) >> 6;
    const int lane = threadIdx.x & 63;
    const int mat = wid >> 9;
    const int k = wid & 511;
    const float* W = mat ? W2 : W1;
    const float* u = ws + OFF_U + (mat ? 0 : OUT_DIM);  // mat0 needs u2, mat1 needs u1
    float2 w = *(const float2*)(W + k * OUT_DIM + 2 * lane);
    float2 uu = *(const float2*)(u + 2 * lane);
    float acc = w.x * uu.x + w.y * uu.y;
#pragma unroll
    for (int off = 32; off > 0; off >>= 1) acc += __shfl_down(acc, off);
    if (lane == 0) wv[mat * IN_DIM + k] = acc;
}

__device__ __forceinline__ float dot8(float4 a, float4 b, float4 wa, float4 wb) {
    return a.x * wa.x + a.y * wa.y + a.z * wa.z + a.w * wa.w
         + b.x * wb.x + b.y * wb.y + b.z * wb.z + b.w * wb.w;
}

// one wave per node v: handles feat[v] and shuf[v]; packed float2 stores.
__global__ void k_proj(const float* __restrict__ feat, const float* __restrict__ shuf,
                       const float* __restrict__ ws, float2* __restrict__ pA,
                       float2* __restrict__ pB) {
    const int lane = threadIdx.x & 63;
    const int gw = (blockIdx.x * blockDim.x + threadIdx.x) >> 6;
    const int nw = (gridDim.x * blockDim.x) >> 6;
    const int kA = 4 * lane;
    const int kB = 256 + 4 * lane;
    const float* wv = ws + OFF_WV;
    const float4 w12a = *(const float4*)(wv + kA);
    const float4 w12b = *(const float4*)(wv + kB);
    const float4 w21a = *(const float4*)(wv + IN_DIM + kA);
    const float4 w21b = *(const float4*)(wv + IN_DIM + kB);
    for (int v = gw; v < N_NODES; v += nw) {
        const float* rf = feat + (size_t)v * IN_DIM;
        float4 fa = *(const float4*)(rf + kA);
        float4 fb = *(const float4*)(rf + kB);
        float d12f = dot8(fa, fb, w12a, w12b);
        float d21f = dot8(fa, fb, w21a, w21b);
        const float* rs = shuf + (size_t)v * IN_DIM;
        float4 sa = *(const float4*)(rs + kA);
        float4 sb = *(const float4*)(rs + kB);
        float d12s = dot8(sa, sb, w12a, w12b);
        float d21s = dot8(sa, sb, w21a, w21b);
#pragma unroll
        for (int off = 32; off > 0; off >>= 1) {
            d12f += __shfl_down(d12f, off);
            d21f += __shfl_down(d21f, off);
            d12s += __shfl_down(d12s, off);
            d21s += __shfl_down(d21s, off);
        }
        if (lane == 0) {
            pA[v] = make_float2(d21f, d21s);   // {p_f2, p_s2}
            pB[v] = make_float2(d12f, d12s);   // {p_f1, p_s1}
        }
    }
}

// replica-accumulating scatter: 2 edges/thread, per-wave replica.
__global__ void k_scatter(const int* __restrict__ src1, const int* __restrict__ dst1,
                          const int* __restrict__ src2, const int* __restrict__ dst2,
                          const float2* __restrict__ pA, const float2* __restrict__ pB,
                          float* __restrict__ acc, int rmask) {
    int i = blockIdx.x * blockDim.x + threadIdx.x;
    int r = (i >> 6) & rmask;
    float* aA = acc + (size_t)r * 400000;
    float* aB = aA + 200000;
    int e = 2 * i;
    if (e < N_EDGES) {
        int2 s1 = *(const int2*)(src1 + e);
        int2 d1 = *(const int2*)(dst1 + e);
        int2 s2 = *(const int2*)(src2 + e);
        int2 d2 = *(const int2*)(dst2 + e);
        float2 a0 = pA[s2.x];
        float2 a1 = pA[s2.y];
        float2 b0 = pB[s1.x];
        float2 b1 = pB[s1.y];
        atomicAdd(&aA[2 * d2.x],     a0.x);
        atomicAdd(&aA[2 * d2.x + 1], a0.y);
        atomicAdd(&aA[2 * d2.y],     a1.x);
        atomicAdd(&aA[2 * d2.y + 1], a1.y);
        atomicAdd(&aB[2 * d1.x],     b0.x);
        atomicAdd(&aB[2 * d1.x + 1], b0.y);
        atomicAdd(&aB[2 * d1.y],     b1.x);
        atomicAdd(&aB[2 * d1.y + 1], b1.y);
    }
}

// fallback: atomics straight into out (out pre-inited with alpha)
__global__ void k_scatter_direct(const int* __restrict__ src1, const int* __restrict__ dst1,
                                 const int* __restrict__ src2, const int* __restrict__ dst2,
                                 const float2* __restrict__ pA, const float2* __restrict__ pB,
                                 float* __restrict__ out) {
    int i = blockIdx.x * blockDim.x + threadIdx.x;
    int e = 2 * i;
    if (e < N_EDGES) {
        int2 s1 = *(const int2*)(src1 + e);
        int2 d1 = *(const int2*)(dst1 + e);
        int2 s2 = *(const int2*)(src2 + e);
        int2 d2 = *(const int2*)(dst2 + e);
        float2 a0 = pA[s2.x];
        float2 a1 = pA[s2.y];
        float2 b0 = pB[s1.x];
        float2 b1 = pB[s1.y];
        atomicAdd(&out[d2.x],                 a0.x);
        atomicAdd(&out[2 * N_NODES + d2.x],   a0.y);
        atomicAdd(&out[d2.y],                 a1.x);
        atomicAdd(&out[2 * N_NODES + d2.y],   a1.y);
        atomicAdd(&out[N_NODES + d1.x],       b0.x);
        atomicAdd(&out[3 * N_NODES + d1.x],   b0.y);
        atomicAdd(&out[N_NODES + d1.y],       b1.x);
        atomicAdd(&out[3 * N_NODES + d1.y],   b1.y);
    }
}

__global__ void k_init(float* __restrict__ out, const float* __restrict__ ws) {
    int i = blockIdx.x * blockDim.x + threadIdx.x;
    if (i < 4 * N_NODES) {
        int sec = i / N_NODES;
        out[i] = ws[OFF_ALPHA + (sec & 1)];
    }
}

__global__ void k_final(const float* __restrict__ acc, const float* __restrict__ ws,
                        float* __restrict__ out, int R) {
    int v = blockIdx.x * blockDim.x + threadIdx.x;
    if (v < N_NODES) {
        float a0 = ws[OFF_ALPHA], a1 = ws[OFF_ALPHA + 1];
        float t1 = 0.f, t2 = 0.f, t3 = 0.f, t4 = 0.f;
        for (int r = 0; r < R; ++r) {
            const float2* aA = (const float2*)(acc + (size_t)r * 400000);
            const float2* aB = aA + 100000;
            float2 x = aA[v];
            float2 y = aB[v];
            t1 += x.x; t3 += x.y;
            t2 += y.x; t4 += y.y;
        }
        out[v]               = a0 + t1;
        out[N_NODES + v]     = a1 + t2;
        out[2 * N_NODES + v] = a0 + t3;
        out[3 * N_NODES + v] = a1 + t4;
    }
}

extern "C" void kernel_launch(void* const* d_in, const int* in_sizes, int n_in,
                              void* d_out, int out_size, void* d_ws, size_t ws_size,
                              hipStream_t stream) {
    const float* feat = (const float*)d_in[0];
    const float* shuf = (const float*)d_in[1];
    const int* src1 = (const int*)d_in[2];
    const int* dst1 = (const int*)d_in[3];
    const int* src2 = (const int*)d_in[4];
    const int* dst2 = (const int*)d_in[5];
    const float* W1 = (const float*)d_in[6];
    const float* b1 = (const float*)d_in[7];
    const float* W2 = (const float*)d_in[8];
    const float* b2 = (const float*)d_in[9];
    const float* Wb = (const float*)d_in[10];
    const float* bb = (const float*)d_in[11];
    float* out = (float*)d_out;

    float* wsf = (float*)d_ws;
    size_t avail = ws_size / 4;  // floats

    // pick replica count that fits ws
    int R = 0;
    for (int r = 8; r >= 1; r >>= 1) {
        if ((size_t)OFF_DEG + (size_t)r * 600000 <= avail) { R = r; break; }
    }
    const int Rdeg = (R >= 1) ? R : 1;

    int* deg = (int*)(wsf + OFF_DEG);
    float* acc = wsf + OFF_DEG + (size_t)Rdeg * 200000;
    float2* pA = (float2*)(wsf + OFF_PA);
    float2* pB = (float2*)(wsf + OFF_PB);

    long tailf = (long)Rdeg * 200000 + (R >= 1 ? (long)R * 400000 : 0);
    k_zero<<<4096, 256, 0, stream>>>((float4*)wsf, (float4*)(wsf + OFF_DEG), 1536 / 4, tailf / 4);
    k_deg<<<(N_EDGES / 2 + 255) / 256, 256, 0, stream>>>(src1, src2, deg, Rdeg - 1);
    k_wsum<<<2048, 128, 0, stream>>>(feat, deg, Rdeg, wsf + OFF_S1, wsf + OFF_S2);
    k_gemv_m<<<dim3(16, 2), 128, 0, stream>>>(wsf, W1, W2, wsf + OFF_M);
    k_u<<<2, 128, 0, stream>>>(wsf, b1, b2, Wb, bb);
    k_w<<<256, 256, 0, stream>>>(wsf, W1, W2, wsf + OFF_WV);
    k_proj<<<8192, 256, 0, stream>>>(feat, shuf, wsf, pA, pB);
    if (R >= 1) {
        k_scatter<<<(N_EDGES / 2 + 255) / 256, 256, 0, stream>>>(src1, dst1, src2, dst2,
                                                                 pA, pB, acc, R - 1);
        k_final<<<(N_NODES + 255) / 256, 256, 0, stream>>>(acc, wsf, out, R);
    } else {
        k_init<<<(4 * N_NODES + 255) / 256, 256, 0, stream>>>(out, wsf);
        k_scatter_direct<<<(N_EDGES / 2 + 255) / 256, 256, 0, stream>>>(src1, dst1, src2, dst2,
                                                                        pA, pB, out);
    }
}

// Round 3
// 836.417 us; speedup vs baseline: 1.3618x; 1.3339x over previous
//
#include <hip/hip_runtime.h>
#include <math.h>

#define N_NODES 100000
#define N_EDGES 1600000
#define IN_DIM  512
#define OUT_DIM 128

// ---------------- ws layout (float offsets) ----------------
#define OFF_S1    0        // 512
#define OFF_S2    512      // 512
#define OFF_M     1024     // 256: m[2][128]
#define OFF_U     1280     // 256: u[2][128]
#define OFF_WV    1536     // 1024: w12[512] | w21[512]
#define OFF_ALPHA 2560     // 2
#define OFF_PA    4096     // float2[N]: {p_f2, p_s2}   (graph2 table)
#define OFF_PB    204096   // float2[N]: {p_f1, p_s1}   (graph1 table)
#define OFF_DEGR  404096   // int[2][100000] reduced degrees
#define OFF_BUF   604096   // degbuf: Cd*200000 ints, then scbuf: Cs*400000 floats

#define P_SC   8192        // nodes per scatter partition (2 sections * 8192 * 4B = 64KB LDS)
#define NP_SC  13          // ceil(100000/8192)
#define P_D    16384       // nodes per degree partition (16384 * 4B = 64KB LDS)
#define NP_D   7           // ceil(100000/16384)

__global__ void k_zero(float* __restrict__ p, long n) {
    long i = (long)blockIdx.x * blockDim.x + threadIdx.x;
    long stride = (long)gridDim.x * blockDim.x;
    for (long j = i; j < n; j += stride) p[j] = 0.0f;
}

// ---- binned degree histogram: grid(NP_D*Cd, 2), 512 thr, 64KB LDS, NO global atomics
__global__ __launch_bounds__(512) void k_deg_b(const int* __restrict__ src1,
                                               const int* __restrict__ src2,
                                               int* __restrict__ degbuf, int Cd) {
    __shared__ int bins[P_D];
    const int part = blockIdx.x % NP_D;
    const int c    = blockIdx.x / NP_D;
    const int g    = blockIdx.y;
    const int tid  = threadIdx.x;
    const int base = part * P_D;
    const int4* srcv = (const int4*)(g ? src2 : src1);
    for (int i = tid; i < P_D; i += 512) bins[i] = 0;
    __syncthreads();
    const long E4 = N_EDGES / 4;
    const long s4 = ((long)c * E4) / Cd;
    const long e4 = ((long)(c + 1) * E4) / Cd;
    for (long i = s4 + tid; i < e4; i += 512) {
        int4 s = srcv[i];
        unsigned l0 = (unsigned)(s.x - base), l1 = (unsigned)(s.y - base);
        unsigned l2 = (unsigned)(s.z - base), l3 = (unsigned)(s.w - base);
        if (l0 < P_D) atomicAdd(&bins[l0], 1);
        if (l1 < P_D) atomicAdd(&bins[l1], 1);
        if (l2 < P_D) atomicAdd(&bins[l2], 1);
        if (l3 < P_D) atomicAdd(&bins[l3], 1);
    }
    __syncthreads();
    const int valid = min(P_D, N_NODES - base);
    int* o = degbuf + (size_t)c * 200000 + (size_t)g * 100000 + base;
    for (int l = tid; l < valid; l += 512) o[l] = bins[l];
}

__global__ void k_degred(const int* __restrict__ degbuf, int* __restrict__ degr, int Cd) {
    int j = blockIdx.x * blockDim.x + threadIdx.x;
    if (j < 200000) {
        int acc = 0;
        for (int c = 0; c < Cd; ++c) acc += degbuf[(size_t)c * 200000 + j];
        degr[j] = acc;
    }
}

// 128 threads/block; thread t owns dims [4t,4t+4).
__global__ void k_wsum(const float* __restrict__ feat, const int* __restrict__ degr,
                       float* __restrict__ s1, float* __restrict__ s2) {
    const int k = 4 * threadIdx.x;
    float4 a1 = {0.f, 0.f, 0.f, 0.f};
    float4 a2 = {0.f, 0.f, 0.f, 0.f};
    for (int v = blockIdx.x; v < N_NODES; v += gridDim.x) {
        float d1 = (float)degr[v];
        float d2 = (float)degr[100000 + v];
        float4 f = *reinterpret_cast<const float4*>(feat + (size_t)v * IN_DIM + k);
        a1.x += d1 * f.x; a1.y += d1 * f.y; a1.z += d1 * f.z; a1.w += d1 * f.w;
        a2.x += d2 * f.x; a2.y += d2 * f.y; a2.z += d2 * f.z; a2.w += d2 * f.w;
    }
    atomicAdd(&s1[k],     a1.x); atomicAdd(&s1[k + 1], a1.y);
    atomicAdd(&s1[k + 2], a1.z); atomicAdd(&s1[k + 3], a1.w);
    atomicAdd(&s2[k],     a2.x); atomicAdd(&s2[k + 1], a2.y);
    atomicAdd(&s2[k + 2], a2.z); atomicAdd(&s2[k + 3], a2.w);
}

__global__ void k_gemv_m(const float* __restrict__ ws, const float* __restrict__ W1,
                         const float* __restrict__ W2, float* __restrict__ m) {
    const int mat = blockIdx.y;
    const float* W = mat ? W2 : W1;
    const float* s = ws + (mat ? OFF_S2 : OFF_S1);
    const int t = threadIdx.x;
    const int k0 = blockIdx.x * 32;
    float acc = 0.f;
#pragma unroll 8
    for (int j = 0; j < 32; ++j)
        acc += s[k0 + j] * W[(k0 + j) * OUT_DIM + t];
    atomicAdd(&m[mat * OUT_DIM + t], acc);
}

__global__ void k_u(float* __restrict__ ws, const float* __restrict__ b1,
                    const float* __restrict__ b2, const float* __restrict__ Wb,
                    const float* __restrict__ bb) {
    __shared__ float c[OUT_DIM];
    __shared__ float red[128];
    const int mat = blockIdx.x;
    const int t = threadIdx.x;
    const float* b = mat ? b2 : b1;
    float mv = ws[OFF_M + mat * OUT_DIM + t] * (1.0f / N_NODES) + b[t];
    c[t] = 1.0f / (1.0f + expf(-mv));
    __syncthreads();
    float acc = 0.f;
    const float4* wr = (const float4*)(Wb + t * OUT_DIM);
#pragma unroll 8
    for (int j = 0; j < OUT_DIM / 4; ++j) {
        float4 w = wr[j];
        acc += w.x * c[4 * j] + w.y * c[4 * j + 1] + w.z * c[4 * j + 2] + w.w * c[4 * j + 3];
    }
    ws[OFF_U + mat * OUT_DIM + t] = acc;   // mat0: u1, mat1: u2
    const float* bo = mat ? b1 : b2;       // alpha0 = b2.u1+bb ; alpha1 = b1.u2+bb
    red[t] = bo[t] * acc;
    __syncthreads();
    for (int s = 64; s > 0; s >>= 1) {
        if (t < s) red[t] += red[t + s];
        __syncthreads();
    }
    if (t == 0) ws[OFF_ALPHA + mat] = red[0] + bb[0];
}

__global__ void k_w(const float* __restrict__ ws, const float* __restrict__ W1,
                    const float* __restrict__ W2, float* __restrict__ wv) {
    const int wid = (blockIdx.x * blockDim.x + threadIdx.x) >> 6;
    const int lane = threadIdx.x & 63;
    const int mat = wid >> 9;
    const int k = wid & 511;
    const float* W = mat ? W2 : W1;
    const float* u = ws + OFF_U + (mat ? 0 : OUT_DIM);  // mat0 needs u2, mat1 needs u1
    float2 w = *(const float2*)(W + k * OUT_DIM + 2 * lane);
    float2 uu = *(const float2*)(u + 2 * lane);
    float acc = w.x * uu.x + w.y * uu.y;
#pragma unroll
    for (int off = 32; off > 0; off >>= 1) acc += __shfl_down(acc, off);
    if (lane == 0) wv[mat * IN_DIM + k] = acc;
}

__device__ __forceinline__ float dot8(float4 a, float4 b, float4 wa, float4 wb) {
    return a.x * wa.x + a.y * wa.y + a.z * wa.z + a.w * wa.w
         + b.x * wb.x + b.y * wb.y + b.z * wb.z + b.w * wb.w;
}

__global__ void k_proj(const float* __restrict__ feat, const float* __restrict__ shuf,
                       const float* __restrict__ ws, float2* __restrict__ pA,
                       float2* __restrict__ pB) {
    const int lane = threadIdx.x & 63;
    const int gw = (blockIdx.x * blockDim.x + threadIdx.x) >> 6;
    const int nw = (gridDim.x * blockDim.x) >> 6;
    const int kA = 4 * lane;
    const int kB = 256 + 4 * lane;
    const float* wv = ws + OFF_WV;
    const float4 w12a = *(const float4*)(wv + kA);
    const float4 w12b = *(const float4*)(wv + kB);
    const float4 w21a = *(const float4*)(wv + IN_DIM + kA);
    const float4 w21b = *(const float4*)(wv + IN_DIM + kB);
    for (int v = gw; v < N_NODES; v += nw) {
        const float* rf = feat + (size_t)v * IN_DIM;
        float4 fa = *(const float4*)(rf + kA);
        float4 fb = *(const float4*)(rf + kB);
        float d12f = dot8(fa, fb, w12a, w12b);
        float d21f = dot8(fa, fb, w21a, w21b);
        const float* rs = shuf + (size_t)v * IN_DIM;
        float4 sa = *(const float4*)(rs + kA);
        float4 sb = *(const float4*)(rs + kB);
        float d12s = dot8(sa, sb, w12a, w12b);
        float d21s = dot8(sa, sb, w21a, w21b);
#pragma unroll
        for (int off = 32; off > 0; off >>= 1) {
            d12f += __shfl_down(d12f, off);
            d21f += __shfl_down(d21f, off);
            d12s += __shfl_down(d12s, off);
            d21s += __shfl_down(d21s, off);
        }
        if (lane == 0) {
            pA[v] = make_float2(d21f, d21s);   // {p_f2, p_s2}
            pB[v] = make_float2(d12f, d12s);   // {p_f1, p_s1}
        }
    }
}

// ---- binned scatter: grid(NP_SC*Cs, 2), 512 thr, 64KB LDS, NO global atomics
// g=0: graph1 edges (dst1) -> sections 1 (p_f1) and 3 (p_s1), table pB
// g=1: graph2 edges (dst2) -> sections 0 (p_f2) and 2 (p_s2), table pA
__global__ __launch_bounds__(512) void k_sc_b(const int* __restrict__ src1,
                                              const int* __restrict__ dst1,
                                              const int* __restrict__ src2,
                                              const int* __restrict__ dst2,
                                              const float2* __restrict__ pA,
                                              const float2* __restrict__ pB,
                                              float* __restrict__ scbuf, int Cs) {
    __shared__ float bins[2 * P_SC];
    const int part = blockIdx.x % NP_SC;
    const int c    = blockIdx.x / NP_SC;
    const int g    = blockIdx.y;
    const int tid  = threadIdx.x;
    const int base = part * P_SC;
    const int4* dstv = (const int4*)(g ? dst2 : dst1);
    const int4* srcv = (const int4*)(g ? src2 : src1);
    const float2* tab = g ? pA : pB;
    for (int i = tid; i < 2 * P_SC; i += 512) bins[i] = 0.f;
    __syncthreads();
    const long E4 = N_EDGES / 4;
    const long s4 = ((long)c * E4) / Cs;
    const long e4 = ((long)(c + 1) * E4) / Cs;
    for (long i = s4 + tid; i < e4; i += 512) {
        int4 d = dstv[i];
        unsigned l0 = (unsigned)(d.x - base), l1 = (unsigned)(d.y - base);
        unsigned l2 = (unsigned)(d.z - base), l3 = (unsigned)(d.w - base);
        bool h0 = l0 < P_SC, h1 = l1 < P_SC, h2 = l2 < P_SC, h3 = l3 < P_SC;
        if (h0 | h1 | h2 | h3) {
            int4 s = srcv[i];
            if (h0) { float2 p = tab[s.x]; atomicAdd(&bins[l0], p.x); atomicAdd(&bins[P_SC + l0], p.y); }
            if (h1) { float2 p = tab[s.y]; atomicAdd(&bins[l1], p.x); atomicAdd(&bins[P_SC + l1], p.y); }
            if (h2) { float2 p = tab[s.z]; atomicAdd(&bins[l2], p.x); atomicAdd(&bins[P_SC + l2], p.y); }
            if (h3) { float2 p = tab[s.w]; atomicAdd(&bins[l3], p.x); atomicAdd(&bins[P_SC + l3], p.y); }
        }
    }
    __syncthreads();
    const int valid = min(P_SC, N_NODES - base);
    const int secA = g ? 0 : 1;
    const int secB = g ? 2 : 3;
    float* oA = scbuf + ((size_t)c * 4 + secA) * 100000 + base;
    float* oB = scbuf + ((size_t)c * 4 + secB) * 100000 + base;
    for (int l = tid; l < valid; l += 512) {
        oA[l] = bins[l];
        oB[l] = bins[P_SC + l];
    }
}

__global__ void k_final(const float* __restrict__ scbuf, const float* __restrict__ ws,
                        float* __restrict__ out, int Cs) {
    int i = blockIdx.x * blockDim.x + threadIdx.x;
    if (i < 4 * N_NODES) {
        int sec = i / N_NODES;
        int v = i - sec * N_NODES;
        float t = 0.f;
        for (int c = 0; c < Cs; ++c) t += scbuf[((size_t)c * 4 + sec) * 100000 + v];
        out[i] = ws[OFF_ALPHA + (sec & 1)] + t;
    }
}

// ---------------- fallback (small ws): direct global atomics ----------------
__global__ void k_deg_direct(const int* __restrict__ src1, const int* __restrict__ src2,
                             int* __restrict__ degr) {
    int i = blockIdx.x * blockDim.x + threadIdx.x;
    if (i < N_EDGES) {
        atomicAdd(&degr[src1[i]], 1);
        atomicAdd(&degr[100000 + src2[i]], 1);
    }
}

__global__ void k_init(float* __restrict__ out, const float* __restrict__ ws) {
    int i = blockIdx.x * blockDim.x + threadIdx.x;
    if (i < 4 * N_NODES) {
        int sec = i / N_NODES;
        out[i] = ws[OFF_ALPHA + (sec & 1)];
    }
}

__global__ void k_scatter_direct(const int* __restrict__ src1, const int* __restrict__ dst1,
                                 const int* __restrict__ src2, const int* __restrict__ dst2,
                                 const float2* __restrict__ pA, const float2* __restrict__ pB,
                                 float* __restrict__ out) {
    int i = blockIdx.x * blockDim.x + threadIdx.x;
    if (i < N_EDGES) {
        int s1 = src1[i], d1 = dst1[i];
        int s2 = src2[i], d2 = dst2[i];
        float2 a = pA[s2];
        float2 b = pB[s1];
        atomicAdd(&out[d2],                 a.x);
        atomicAdd(&out[2 * N_NODES + d2],   a.y);
        atomicAdd(&out[N_NODES + d1],       b.x);
        atomicAdd(&out[3 * N_NODES + d1],   b.y);
    }
}

extern "C" void kernel_launch(void* const* d_in, const int* in_sizes, int n_in,
                              void* d_out, int out_size, void* d_ws, size_t ws_size,
                              hipStream_t stream) {
    const float* feat = (const float*)d_in[0];
    const float* shuf = (const float*)d_in[1];
    const int* src1 = (const int*)d_in[2];
    const int* dst1 = (const int*)d_in[3];
    const int* src2 = (const int*)d_in[4];
    const int* dst2 = (const int*)d_in[5];
    const float* W1 = (const float*)d_in[6];
    const float* b1 = (const float*)d_in[7];
    const float* W2 = (const float*)d_in[8];
    const float* b2 = (const float*)d_in[9];
    const float* Wb = (const float*)d_in[10];
    const float* bb = (const float*)d_in[11];
    float* out = (float*)d_out;

    float* wsf = (float*)d_ws;
    float2* pA = (float2*)(wsf + OFF_PA);
    float2* pB = (float2*)(wsf + OFF_PB);
    int* degr = (int*)(wsf + OFF_DEGR);

    long availf = (long)(ws_size / 4);
    long budget = availf - OFF_BUF;
    int Cd = 0, Cs = 0;
    if (budget >= 600000) {
        Cs = (int)((budget / 2) / 400000); if (Cs > 20) Cs = 20; if (Cs < 1) Cs = 1;
        Cd = (int)((budget - (long)Cs * 400000) / 200000); if (Cd > 36) Cd = 36; if (Cd < 1) Cd = 1;
    }

    if (Cd >= 1) {
        int* degbuf = (int*)(wsf + OFF_BUF);
        float* scbuf = wsf + OFF_BUF + (long)Cd * 200000;
        // zero only the tiny atomic accumulators (s1,s2,m)
        k_zero<<<2, 512, 0, stream>>>(wsf, 1280);
        k_deg_b<<<dim3(NP_D * Cd, 2), 512, 0, stream>>>(src1, src2, degbuf, Cd);
        k_degred<<<(200000 + 255) / 256, 256, 0, stream>>>(degbuf, degr, Cd);
        k_wsum<<<2048, 128, 0, stream>>>(feat, degr, wsf + OFF_S1, wsf + OFF_S2);
        k_gemv_m<<<dim3(16, 2), 128, 0, stream>>>(wsf, W1, W2, wsf + OFF_M);
        k_u<<<2, 128, 0, stream>>>(wsf, b1, b2, Wb, bb);
        k_w<<<256, 256, 0, stream>>>(wsf, W1, W2, wsf + OFF_WV);
        k_proj<<<8192, 256, 0, stream>>>(feat, shuf, wsf, pA, pB);
        k_sc_b<<<dim3(NP_SC * Cs, 2), 512, 0, stream>>>(src1, dst1, src2, dst2, pA, pB, scbuf, Cs);
        k_final<<<(4 * N_NODES + 255) / 256, 256, 0, stream>>>(scbuf, wsf, out, Cs);
    } else {
        // fallback: direct atomics
        k_zero<<<2, 512, 0, stream>>>(wsf, 1280);
        k_zero<<<256, 256, 0, stream>>>((float*)degr, 200000);
        k_deg_direct<<<(N_EDGES + 255) / 256, 256, 0, stream>>>(src1, src2, degr);
        k_wsum<<<2048, 128, 0, stream>>>(feat, degr, wsf + OFF_S1, wsf + OFF_S2);
        k_gemv_m<<<dim3(16, 2), 128, 0, stream>>>(wsf, W1, W2, wsf + OFF_M);
        k_u<<<2, 128, 0, stream>>>(wsf, b1, b2, Wb, bb);
        k_w<<<256, 256, 0, stream>>>(wsf, W1, W2, wsf + OFF_WV);
        k_proj<<<8192, 256, 0, stream>>>(feat, shuf, wsf, pA, pB);
        k_init<<<(4 * N_NODES + 255) / 256, 256, 0, stream>>>(out, wsf);
        k_scatter_direct<<<(N_EDGES + 255) / 256, 256, 0, stream>>>(src1, dst1, src2, dst2, pA, pB, out);
    }
}

// Round 4
// 656.682 us; speedup vs baseline: 1.7345x; 1.2737x over previous
//
#include <hip/hip_runtime.h>
#include <math.h>

#define N_NODES 100000
#define N_EDGES 1600000
#define IN_DIM  512
#define OUT_DIM 128

// ---------------- ws layout (float offsets) ----------------
#define OFF_S1    0        // 512  (s1 | s2 contiguous: 1024 floats)
#define OFF_S2    512      // 512
#define OFF_M     1024     // 256: m[2][128]
#define OFF_U     1280     // 256: u[2][128]
#define OFF_WV    1536     // 1024: w12[512] | w21[512]
#define OFF_ALPHA 2560     // 2
#define OFF_PA    4096     // float2[N]: {p_f2, p_s2}   (graph2 table)
#define OFF_PB    204096   // float2[N]: {p_f1, p_s1}   (graph1 table)
#define OFF_DEGR  404096   // int[2][100000] reduced degrees
#define OFF_BUF   604096   // degbuf: Cd*200000 ints -> dead after k_degred, then
                           // pbuf: 1024*1024 floats (aliases degbuf) -> dead after k_sred
                           // scbuf: Cs*400000 floats at OFF_BUF + Cd*200000

#define P_SC   8192        // nodes per scatter partition (2 * 8192 * 4B = 64KB LDS)
#define NP_SC  13          // ceil(100000/8192)
#define P_D    16384       // nodes per degree partition (16384 * 4B = 64KB LDS)
#define NP_D   7           // ceil(100000/16384)
#define WSUM_NBLK 1024

__global__ void k_zero(float* __restrict__ p, long n) {
    long i = (long)blockIdx.x * blockDim.x + threadIdx.x;
    long stride = (long)gridDim.x * blockDim.x;
    for (long j = i; j < n; j += stride) p[j] = 0.0f;
}

// ---- binned degree histogram: grid(NP_D*Cd, 2), 512 thr, 64KB LDS, NO global atomics
__global__ __launch_bounds__(512) void k_deg_b(const int* __restrict__ src1,
                                               const int* __restrict__ src2,
                                               int* __restrict__ degbuf, int Cd) {
    __shared__ int bins[P_D];
    const int part = blockIdx.x % NP_D;
    const int c    = blockIdx.x / NP_D;
    const int g    = blockIdx.y;
    const int tid  = threadIdx.x;
    const int base = part * P_D;
    const int4* srcv = (const int4*)(g ? src2 : src1);
    for (int i = tid; i < P_D; i += 512) bins[i] = 0;
    __syncthreads();
    const long E4 = N_EDGES / 4;
    const long s4 = ((long)c * E4) / Cd;
    const long e4 = ((long)(c + 1) * E4) / Cd;
    for (long i = s4 + tid; i < e4; i += 512) {
        int4 s = srcv[i];
        unsigned l0 = (unsigned)(s.x - base), l1 = (unsigned)(s.y - base);
        unsigned l2 = (unsigned)(s.z - base), l3 = (unsigned)(s.w - base);
        if (l0 < P_D) atomicAdd(&bins[l0], 1);
        if (l1 < P_D) atomicAdd(&bins[l1], 1);
        if (l2 < P_D) atomicAdd(&bins[l2], 1);
        if (l3 < P_D) atomicAdd(&bins[l3], 1);
    }
    __syncthreads();
    const int valid = min(P_D, N_NODES - base);
    int* o = degbuf + (size_t)c * 200000 + (size_t)g * 100000 + base;
    for (int l = tid; l < valid; l += 512) o[l] = bins[l];
}

__global__ void k_degred(const int* __restrict__ degbuf, int* __restrict__ degr, int Cd) {
    int j = blockIdx.x * blockDim.x + threadIdx.x;
    if (j < 200000) {
        int acc = 0;
        for (int c = 0; c < Cd; ++c) acc += degbuf[(size_t)c * 200000 + j];
        degr[j] = acc;
    }
}

// ---- partial-sum wsum: contiguous chunks, 4-row unroll, plain float4 stores.
// Block b writes pbuf[b*1024 + 0..511] = sum deg1[v]*feat[v][:], [512..1023] for deg2.
__global__ __launch_bounds__(128) void k_wsum_p(const float* __restrict__ feat,
                                                const int* __restrict__ degr,
                                                float* __restrict__ pbuf) {
    const int t = threadIdx.x;
    const int k = 4 * t;
    const int chunk = (N_NODES + WSUM_NBLK - 1) / WSUM_NBLK;   // 98
    const int v0 = blockIdx.x * chunk;
    const int v1 = min(v0 + chunk, N_NODES);
    float4 a1 = {0.f, 0.f, 0.f, 0.f};
    float4 a2 = {0.f, 0.f, 0.f, 0.f};
    const float* fp = feat + (size_t)v0 * IN_DIM + k;
    int v = v0;
    for (; v + 4 <= v1; v += 4, fp += 4 * IN_DIM) {
        float4 f0 = *(const float4*)(fp);
        float4 f1 = *(const float4*)(fp + IN_DIM);
        float4 f2 = *(const float4*)(fp + 2 * IN_DIM);
        float4 f3 = *(const float4*)(fp + 3 * IN_DIM);
        float d10 = (float)degr[v],     d20 = (float)degr[100000 + v];
        float d11 = (float)degr[v + 1], d21 = (float)degr[100000 + v + 1];
        float d12 = (float)degr[v + 2], d22 = (float)degr[100000 + v + 2];
        float d13 = (float)degr[v + 3], d23 = (float)degr[100000 + v + 3];
        a1.x += d10 * f0.x + d11 * f1.x + d12 * f2.x + d13 * f3.x;
        a1.y += d10 * f0.y + d11 * f1.y + d12 * f2.y + d13 * f3.y;
        a1.z += d10 * f0.z + d11 * f1.z + d12 * f2.z + d13 * f3.z;
        a1.w += d10 * f0.w + d11 * f1.w + d12 * f2.w + d13 * f3.w;
        a2.x += d20 * f0.x + d21 * f1.x + d22 * f2.x + d23 * f3.x;
        a2.y += d20 * f0.y + d21 * f1.y + d22 * f2.y + d23 * f3.y;
        a2.z += d20 * f0.z + d21 * f1.z + d22 * f2.z + d23 * f3.z;
        a2.w += d20 * f0.w + d21 * f1.w + d22 * f2.w + d23 * f3.w;
    }
    for (; v < v1; ++v, fp += IN_DIM) {
        float4 f = *(const float4*)(fp);
        float d1 = (float)degr[v], d2 = (float)degr[100000 + v];
        a1.x += d1 * f.x; a1.y += d1 * f.y; a1.z += d1 * f.z; a1.w += d1 * f.w;
        a2.x += d2 * f.x; a2.y += d2 * f.y; a2.z += d2 * f.z; a2.w += d2 * f.w;
    }
    float* o = pbuf + (size_t)blockIdx.x * 1024;
    *(float4*)(o + k) = a1;           // zeros for empty blocks (pbuf is poisoned!)
    *(float4*)(o + 512 + k) = a2;
}

// grid (4,16) x 256: dim d = bx*256+t; sum 64 block-partials; 16-deep atomic chain only.
__global__ void k_sred(const float* __restrict__ pbuf, float* __restrict__ s) {
    const int d = blockIdx.x * 256 + threadIdx.x;
    const int b0 = blockIdx.y * 64;
    float acc = 0.f;
#pragma unroll 8
    for (int b = 0; b < 64; ++b) acc += pbuf[(size_t)(b0 + b) * 1024 + d];
    atomicAdd(&s[d], acc);
}

__global__ void k_gemv_m(const float* __restrict__ ws, const float* __restrict__ W1,
                         const float* __restrict__ W2, float* __restrict__ m) {
    const int mat = blockIdx.y;
    const float* W = mat ? W2 : W1;
    const float* s = ws + (mat ? OFF_S2 : OFF_S1);
    const int t = threadIdx.x;
    const int k0 = blockIdx.x * 32;
    float acc = 0.f;
#pragma unroll 8
    for (int j = 0; j < 32; ++j)
        acc += s[k0 + j] * W[(k0 + j) * OUT_DIM + t];
    atomicAdd(&m[mat * OUT_DIM + t], acc);
}

__global__ void k_u(float* __restrict__ ws, const float* __restrict__ b1,
                    const float* __restrict__ b2, const float* __restrict__ Wb,
                    const float* __restrict__ bb) {
    __shared__ float c[OUT_DIM];
    __shared__ float red[128];
    const int mat = blockIdx.x;
    const int t = threadIdx.x;
    const float* b = mat ? b2 : b1;
    float mv = ws[OFF_M + mat * OUT_DIM + t] * (1.0f / N_NODES) + b[t];
    c[t] = 1.0f / (1.0f + expf(-mv));
    __syncthreads();
    float acc = 0.f;
    const float4* wr = (const float4*)(Wb + t * OUT_DIM);
#pragma unroll 8
    for (int j = 0; j < OUT_DIM / 4; ++j) {
        float4 w = wr[j];
        acc += w.x * c[4 * j] + w.y * c[4 * j + 1] + w.z * c[4 * j + 2] + w.w * c[4 * j + 3];
    }
    ws[OFF_U + mat * OUT_DIM + t] = acc;   // mat0: u1, mat1: u2
    const float* bo = mat ? b1 : b2;       // alpha0 = b2.u1+bb ; alpha1 = b1.u2+bb
    red[t] = bo[t] * acc;
    __syncthreads();
    for (int s = 64; s > 0; s >>= 1) {
        if (t < s) red[t] += red[t + s];
        __syncthreads();
    }
    if (t == 0) ws[OFF_ALPHA + mat] = red[0] + bb[0];
}

__global__ void k_w(const float* __restrict__ ws, const float* __restrict__ W1,
                    const float* __restrict__ W2, float* __restrict__ wv) {
    const int wid = (blockIdx.x * blockDim.x + threadIdx.x) >> 6;
    const int lane = threadIdx.x & 63;
    const int mat = wid >> 9;
    const int k = wid & 511;
    const float* W = mat ? W2 : W1;
    const float* u = ws + OFF_U + (mat ? 0 : OUT_DIM);  // mat0 needs u2, mat1 needs u1
    float2 w = *(const float2*)(W + k * OUT_DIM + 2 * lane);
    float2 uu = *(const float2*)(u + 2 * lane);
    float acc = w.x * uu.x + w.y * uu.y;
#pragma unroll
    for (int off = 32; off > 0; off >>= 1) acc += __shfl_down(acc, off);
    if (lane == 0) wv[mat * IN_DIM + k] = acc;
}

__device__ __forceinline__ float dot8(float4 a, float4 b, float4 wa, float4 wb) {
    return a.x * wa.x + a.y * wa.y + a.z * wa.z + a.w * wa.w
         + b.x * wb.x + b.y * wb.y + b.z * wb.z + b.w * wb.w;
}

__global__ void k_proj(const float* __restrict__ feat, const float* __restrict__ shuf,
                       const float* __restrict__ ws, float2* __restrict__ pA,
                       float2* __restrict__ pB) {
    const int lane = threadIdx.x & 63;
    const int gw = (blockIdx.x * blockDim.x + threadIdx.x) >> 6;
    const int nw = (gridDim.x * blockDim.x) >> 6;
    const int kA = 4 * lane;
    const int kB = 256 + 4 * lane;
    const float* wv = ws + OFF_WV;
    const float4 w12a = *(const float4*)(wv + kA);
    const float4 w12b = *(const float4*)(wv + kB);
    const float4 w21a = *(const float4*)(wv + IN_DIM + kA);
    const float4 w21b = *(const float4*)(wv + IN_DIM + kB);
    for (int v = gw; v < N_NODES; v += nw) {
        const float* rf = feat + (size_t)v * IN_DIM;
        float4 fa = *(const float4*)(rf + kA);
        float4 fb = *(const float4*)(rf + kB);
        const float* rs = shuf + (size_t)v * IN_DIM;
        float4 sa = *(const float4*)(rs + kA);
        float4 sb = *(const float4*)(rs + kB);
        float d12f = dot8(fa, fb, w12a, w12b);
        float d21f = dot8(fa, fb, w21a, w21b);
        float d12s = dot8(sa, sb, w12a, w12b);
        float d21s = dot8(sa, sb, w21a, w21b);
#pragma unroll
        for (int off = 32; off > 0; off >>= 1) {
            d12f += __shfl_down(d12f, off);
            d21f += __shfl_down(d21f, off);
            d12s += __shfl_down(d12s, off);
            d21s += __shfl_down(d21s, off);
        }
        if (lane == 0) {
            pA[v] = make_float2(d21f, d21s);   // {p_f2, p_s2}
            pB[v] = make_float2(d12f, d12s);   // {p_f1, p_s1}
        }
    }
}

// ---- binned scatter: grid(NP_SC*Cs, 2), 512 thr, 64KB LDS, NO global atomics
__global__ __launch_bounds__(512) void k_sc_b(const int* __restrict__ src1,
                                              const int* __restrict__ dst1,
                                              const int* __restrict__ src2,
                                              const int* __restrict__ dst2,
                                              const float2* __restrict__ pA,
                                              const float2* __restrict__ pB,
                                              float* __restrict__ scbuf, int Cs) {
    __shared__ float bins[2 * P_SC];
    const int part = blockIdx.x % NP_SC;
    const int c    = blockIdx.x / NP_SC;
    const int g    = blockIdx.y;
    const int tid  = threadIdx.x;
    const int base = part * P_SC;
    const int4* dstv = (const int4*)(g ? dst2 : dst1);
    const int4* srcv = (const int4*)(g ? src2 : src1);
    const float2* tab = g ? pA : pB;
    for (int i = tid; i < 2 * P_SC; i += 512) bins[i] = 0.f;
    __syncthreads();
    const long E4 = N_EDGES / 4;
    const long s4 = ((long)c * E4) / Cs;
    const long e4 = ((long)(c + 1) * E4) / Cs;
    for (long i = s4 + tid; i < e4; i += 512) {
        int4 d = dstv[i];
        unsigned l0 = (unsigned)(d.x - base), l1 = (unsigned)(d.y - base);
        unsigned l2 = (unsigned)(d.z - base), l3 = (unsigned)(d.w - base);
        bool h0 = l0 < P_SC, h1 = l1 < P_SC, h2 = l2 < P_SC, h3 = l3 < P_SC;
        if (h0 | h1 | h2 | h3) {
            int4 s = srcv[i];
            if (h0) { float2 p = tab[s.x]; atomicAdd(&bins[l0], p.x); atomicAdd(&bins[P_SC + l0], p.y); }
            if (h1) { float2 p = tab[s.y]; atomicAdd(&bins[l1], p.x); atomicAdd(&bins[P_SC + l1], p.y); }
            if (h2) { float2 p = tab[s.z]; atomicAdd(&bins[l2], p.x); atomicAdd(&bins[P_SC + l2], p.y); }
            if (h3) { float2 p = tab[s.w]; atomicAdd(&bins[l3], p.x); atomicAdd(&bins[P_SC + l3], p.y); }
        }
    }
    __syncthreads();
    const int valid = min(P_SC, N_NODES - base);
    const int secA = g ? 0 : 1;
    const int secB = g ? 2 : 3;
    float* oA = scbuf + ((size_t)c * 4 + secA) * 100000 + base;
    float* oB = scbuf + ((size_t)c * 4 + secB) * 100000 + base;
    for (int l = tid; l < valid; l += 512) {
        oA[l] = bins[l];
        oB[l] = bins[P_SC + l];
    }
}

__global__ void k_final(const float* __restrict__ scbuf, const float* __restrict__ ws,
                        float* __restrict__ out, int Cs) {
    int i = blockIdx.x * blockDim.x + threadIdx.x;
    if (i < 4 * N_NODES) {
        int sec = i / N_NODES;
        int v = i - sec * N_NODES;
        float t = 0.f;
        for (int c = 0; c < Cs; ++c) t += scbuf[((size_t)c * 4 + sec) * 100000 + v];
        out[i] = ws[OFF_ALPHA + (sec & 1)] + t;
    }
}

// ---------------- fallbacks (small ws) ----------------
__global__ void k_wsum_atomic(const float* __restrict__ feat, const int* __restrict__ degr,
                              float* __restrict__ s1, float* __restrict__ s2) {
    const int k = 4 * threadIdx.x;
    float4 a1 = {0.f, 0.f, 0.f, 0.f};
    float4 a2 = {0.f, 0.f, 0.f, 0.f};
    for (int v = blockIdx.x; v < N_NODES; v += gridDim.x) {
        float d1 = (float)degr[v];
        float d2 = (float)degr[100000 + v];
        float4 f = *reinterpret_cast<const float4*>(feat + (size_t)v * IN_DIM + k);
        a1.x += d1 * f.x; a1.y += d1 * f.y; a1.z += d1 * f.z; a1.w += d1 * f.w;
        a2.x += d2 * f.x; a2.y += d2 * f.y; a2.z += d2 * f.z; a2.w += d2 * f.w;
    }
    atomicAdd(&s1[k],     a1.x); atomicAdd(&s1[k + 1], a1.y);
    atomicAdd(&s1[k + 2], a1.z); atomicAdd(&s1[k + 3], a1.w);
    atomicAdd(&s2[k],     a2.x); atomicAdd(&s2[k + 1], a2.y);
    atomicAdd(&s2[k + 2], a2.z); atomicAdd(&s2[k + 3], a2.w);
}

__global__ void k_deg_direct(const int* __restrict__ src1, const int* __restrict__ src2,
                             int* __restrict__ degr) {
    int i = blockIdx.x * blockDim.x + threadIdx.x;
    if (i < N_EDGES) {
        atomicAdd(&degr[src1[i]], 1);
        atomicAdd(&degr[100000 + src2[i]], 1);
    }
}

__global__ void k_init(float* __restrict__ out, const float* __restrict__ ws) {
    int i = blockIdx.x * blockDim.x + threadIdx.x;
    if (i < 4 * N_NODES) {
        int sec = i / N_NODES;
        out[i] = ws[OFF_ALPHA + (sec & 1)];
    }
}

__global__ void k_scatter_direct(const int* __restrict__ src1, const int* __restrict__ dst1,
                                 const int* __restrict__ src2, const int* __restrict__ dst2,
                                 const float2* __restrict__ pA, const float2* __restrict__ pB,
                                 float* __restrict__ out) {
    int i = blockIdx.x * blockDim.x + threadIdx.x;
    if (i < N_EDGES) {
        int s1 = src1[i], d1 = dst1[i];
        int s2 = src2[i], d2 = dst2[i];
        float2 a = pA[s2];
        float2 b = pB[s1];
        atomicAdd(&out[d2],                 a.x);
        atomicAdd(&out[2 * N_NODES + d2],   a.y);
        atomicAdd(&out[N_NODES + d1],       b.x);
        atomicAdd(&out[3 * N_NODES + d1],   b.y);
    }
}

extern "C" void kernel_launch(void* const* d_in, const int* in_sizes, int n_in,
                              void* d_out, int out_size, void* d_ws, size_t ws_size,
                              hipStream_t stream) {
    const float* feat = (const float*)d_in[0];
    const float* shuf = (const float*)d_in[1];
    const int* src1 = (const int*)d_in[2];
    const int* dst1 = (const int*)d_in[3];
    const int* src2 = (const int*)d_in[4];
    const int* dst2 = (const int*)d_in[5];
    const float* W1 = (const float*)d_in[6];
    const float* b1 = (const float*)d_in[7];
    const float* W2 = (const float*)d_in[8];
    const float* b2 = (const float*)d_in[9];
    const float* Wb = (const float*)d_in[10];
    const float* bb = (const float*)d_in[11];
    float* out = (float*)d_out;

    float* wsf = (float*)d_ws;
    float2* pA = (float2*)(wsf + OFF_PA);
    float2* pB = (float2*)(wsf + OFF_PB);
    int* degr = (int*)(wsf + OFF_DEGR);

    long availf = (long)(ws_size / 4);
    long budget = availf - OFF_BUF;
    int Cd = 0, Cs = 0;
    if (budget >= 600000) {
        Cs = (int)((budget / 2) / 400000); if (Cs > 20) Cs = 20; if (Cs < 1) Cs = 1;
        Cd = (int)((budget - (long)Cs * 400000) / 200000); if (Cd > 36) Cd = 36; if (Cd < 1) Cd = 1;
    }
    const bool pb_ok = (budget >= 1048576);   // pbuf aliases the (dead) degbuf region

    if (Cd >= 1) {
        int* degbuf = (int*)(wsf + OFF_BUF);
        float* pbuf = wsf + OFF_BUF;          // alias: degbuf dead after k_degred
        float* scbuf = wsf + OFF_BUF + (long)Cd * 200000;
        k_zero<<<2, 512, 0, stream>>>(wsf, 1280);   // s1,s2,m accumulators
        k_deg_b<<<dim3(NP_D * Cd, 2), 512, 0, stream>>>(src1, src2, degbuf, Cd);
        k_degred<<<(200000 + 255) / 256, 256, 0, stream>>>(degbuf, degr, Cd);
        if (pb_ok) {
            k_wsum_p<<<WSUM_NBLK, 128, 0, stream>>>(feat, degr, pbuf);
            k_sred<<<dim3(4, 16), 256, 0, stream>>>(pbuf, wsf + OFF_S1);
        } else {
            k_wsum_atomic<<<2048, 128, 0, stream>>>(feat, degr, wsf + OFF_S1, wsf + OFF_S2);
        }
        k_gemv_m<<<dim3(16, 2), 128, 0, stream>>>(wsf, W1, W2, wsf + OFF_M);
        k_u<<<2, 128, 0, stream>>>(wsf, b1, b2, Wb, bb);
        k_w<<<256, 256, 0, stream>>>(wsf, W1, W2, wsf + OFF_WV);
        k_proj<<<8192, 256, 0, stream>>>(feat, shuf, wsf, pA, pB);
        k_sc_b<<<dim3(NP_SC * Cs, 2), 512, 0, stream>>>(src1, dst1, src2, dst2, pA, pB, scbuf, Cs);
        k_final<<<(4 * N_NODES + 255) / 256, 256, 0, stream>>>(scbuf, wsf, out, Cs);
    } else {
        k_zero<<<2, 512, 0, stream>>>(wsf, 1280);
        k_zero<<<256, 256, 0, stream>>>((float*)degr, 200000);
        k_deg_direct<<<(N_EDGES + 255) / 256, 256, 0, stream>>>(src1, src2, degr);
        k_wsum_atomic<<<2048, 128, 0, stream>>>(feat, degr, wsf + OFF_S1, wsf + OFF_S2);
        k_gemv_m<<<dim3(16, 2), 128, 0, stream>>>(wsf, W1, W2, wsf + OFF_M);
        k_u<<<2, 128, 0, stream>>>(wsf, b1, b2, Wb, bb);
        k_w<<<256, 256, 0, stream>>>(wsf, W1, W2, wsf + OFF_WV);
        k_proj<<<8192, 256, 0, stream>>>(feat, shuf, wsf, pA, pB);
        k_init<<<(4 * N_NODES + 255) / 256, 256, 0, stream>>>(out, wsf);
        k_scatter_direct<<<(N_EDGES + 255) / 256, 256, 0, stream>>>(src1, dst1, src2, dst2, pA, pB, out);
    }
}